// Round 8
// baseline (74.977 us; speedup 1.0000x reference)
//
#include <hip/hip_runtime.h>
#include <hip/hip_bf16.h>

// OccupancyGridEMABatched:
//   out[v] = touched(v) ? max(0.95*grid[v], max_{pts at v} occ_val) : grid[v]
//
// R7 post-mortem: coalescing the record flush (WRITE 68->24MB) changed
// NOTHING (52.8 vs 53.1us) -> partition is occupancy/latency-bound
// (Occupancy 16%, 2 blocks/CU grid-limited, ~19 barriers, blocking global
// atomic mid-kernel), not store-bound. R8: attack latency structure:
//   * 4096 pts/block -> 1024 blocks (4/CU), LDS 28KB (5/CU LDS-limit)
//   * scan: 16-barrier Hillis-Steele -> wave __shfl_up scan (2 barriers)
//   * cursor atomicAdd issued BEFORE the scan, consumed after -> latency
//     hidden under scan VALU
// Packed 4B records: (val & 0xFFFFC000) | idx_low14; 18 value bits
// (err ~2^-8 measured, threshold 2e-2). Phase B: LDS atomicMax on packed
// word + fused finalize. Deterministic: per-voxel max is order-insensitive.

#define GRID_R          128
#define EMA_DEC         0.95f
#define NBUCKET         512           // 4 batches * 128 gx-planes
#define VOX_PER_BUCKET  16384         // 128*128 voxels = 64KB LDS
#define BCAP            10240         // records/bucket: mean 8192 + 22 sigma
#define PTS_PER_BLOCK   4096
#define PTS_PER_THREAD  16            // 4096 / 256

__device__ __forceinline__ int quant_clamp(float p) {
    // ((p/2 + 0.5) * 128) truncated; *0.5 and *128 are exact pow2 scalings
    // (FMA contraction cannot change the result since p*0.5f is exact).
    int g = (int)((p * 0.5f + 0.5f) * (float)GRID_R);
    return min(max(g, 0), GRID_R - 1);
}

// ---------------------------------------------------------------- Phase A
__global__ __launch_bounds__(256)
void occ_partition3_kernel(const float* __restrict__ pts,
                           const float* __restrict__ occ_val,
                           const int*   __restrict__ bidx,
                           unsigned*     __restrict__ records,
                           unsigned*     __restrict__ cursors,
                           int n_total) {
    __shared__ unsigned       rec[PTS_PER_BLOCK];    // 16 KB (bucket-sorted)
    __shared__ unsigned short bkt[PTS_PER_BLOCK];    //  8 KB (bucket per slot)
    __shared__ int            cur[NBUCKET];          //  2 KB hist -> cursor
    __shared__ int            gdelta[NBUCKET];       //  2 KB gbase - scanExcl
    __shared__ int            wsum[4];               // per-wave scan totals

    const int tid  = threadIdx.x;
    const int lane = tid & 63;
    const int wv   = tid >> 6;       // wave id 0..3

    for (int b = tid; b < NBUCKET; b += 256) cur[b] = 0;
    __syncthreads();

    const float4* pts4 = reinterpret_cast<const float4*>(pts);
    const float4* ov4  = reinterpret_cast<const float4*>(occ_val);
    const int4*   bi4  = reinterpret_cast<const int4*>(bidx);

    // statically-indexed -> stays in VGPRs (rule #20)
    int pk[PTS_PER_THREAD];
    int bk[PTS_PER_THREAD];

    #pragma unroll
    for (int r = 0; r < PTS_PER_THREAD / 8; ++r) {
        // 8-point group id; block owns groups [blk*512, blk*512+512)
        const int i = blockIdx.x * ((PTS_PER_THREAD / 8) * 256) + r * 256 + tid;
        if (i * 8 + 7 < n_total) {
            float4 q0 = pts4[i * 6 + 0];
            float4 q1 = pts4[i * 6 + 1];
            float4 q2 = pts4[i * 6 + 2];
            float4 q3 = pts4[i * 6 + 3];
            float4 q4 = pts4[i * 6 + 4];
            float4 q5 = pts4[i * 6 + 5];
            float4 oa = ov4[i * 2 + 0];
            float4 ob = ov4[i * 2 + 1];
            int4   ba = bi4[i * 2 + 0];
            int4   bb = bi4[i * 2 + 1];

            float xs[8] = {q0.x, q0.w, q1.z, q2.y, q3.x, q3.w, q4.z, q5.y};
            float ys[8] = {q0.y, q1.x, q1.w, q2.z, q3.y, q4.x, q4.w, q5.z};
            float zs[8] = {q0.z, q1.y, q2.x, q2.w, q3.z, q4.y, q5.x, q5.w};
            int   vb[8] = {__float_as_int(oa.x), __float_as_int(oa.y),
                           __float_as_int(oa.z), __float_as_int(oa.w),
                           __float_as_int(ob.x), __float_as_int(ob.y),
                           __float_as_int(ob.z), __float_as_int(ob.w)};
            int   bs[8] = {ba.x, ba.y, ba.z, ba.w, bb.x, bb.y, bb.z, bb.w};

            #pragma unroll
            for (int k = 0; k < 8; ++k) {
                int gx = quant_clamp(xs[k]);
                int gy = quant_clamp(ys[k]);
                int gz = quant_clamp(zs[k]);
                int idx = bs[k] * (GRID_R * GRID_R * GRID_R)
                        + gx * (GRID_R * GRID_R) + gy * GRID_R + gz;
                pk[r * 8 + k] = (vb[k] & (int)0xFFFFC000) | (idx & 0x3FFF);
                bk[r * 8 + k] = idx >> 14;
            }
        } else {
            #pragma unroll
            for (int k = 0; k < 8; ++k) {
                bk[r * 8 + k] = -1;
                pk[r * 8 + k] = 0;
                int p = i * 8 + k;
                if (p < n_total) {
                    int gx = quant_clamp(pts[p * 3 + 0]);
                    int gy = quant_clamp(pts[p * 3 + 1]);
                    int gz = quant_clamp(pts[p * 3 + 2]);
                    int idx = bidx[p] * (GRID_R * GRID_R * GRID_R)
                            + gx * (GRID_R * GRID_R) + gy * GRID_R + gz;
                    pk[r * 8 + k] = (__float_as_int(occ_val[p]) & (int)0xFFFFC000)
                                  | (idx & 0x3FFF);
                    bk[r * 8 + k] = idx >> 14;
                }
            }
        }
    }

    // block-local histogram
    #pragma unroll
    for (int k = 0; k < PTS_PER_THREAD; ++k)
        if (bk[k] >= 0) atomicAdd(&cur[bk[k]], 1);
    __syncthreads();

    // thread t owns buckets {2t, 2t+1}
    const int a = cur[2 * tid];
    const int c = cur[2 * tid + 1];
    const int s = a + c;

    // issue global reservations NOW; scan below hides the round-trip latency
    unsigned g0 = a ? atomicAdd(&cursors[2 * tid],     (unsigned)a) : 0u;
    unsigned g1 = c ? atomicAdd(&cursors[2 * tid + 1], (unsigned)c) : 0u;

    // wave-level inclusive scan of s (no barriers inside a wave)
    int x = s;
    #pragma unroll
    for (int off = 1; off < 64; off <<= 1) {
        int v = __shfl_up(x, off, 64);
        if (lane >= off) x += v;
    }
    if (lane == 63) wsum[wv] = x;
    __syncthreads();

    const int w0 = wsum[0], w1 = wsum[1], w2 = wsum[2], w3 = wsum[3];
    const int wofs  = (wv > 0 ? w0 : 0) + (wv > 1 ? w1 : 0) + (wv > 2 ? w2 : 0);
    const int total = w0 + w1 + w2 + w3;
    const int excl  = x + wofs - s;     // exclusive prefix of bucket 2t

    // re-init LDS cursors to scan positions; gdelta consumes the atomics'
    // return values (vmcnt drains here, after ~200cy of scan VALU)
    cur[2 * tid]        = excl;
    cur[2 * tid + 1]    = excl + a;
    gdelta[2 * tid]     = (int)g0 - excl;
    gdelta[2 * tid + 1] = (int)g1 - (excl + a);
    __syncthreads();

    // bucket-sort records into LDS
    #pragma unroll
    for (int k = 0; k < PTS_PER_THREAD; ++k) {
        if (bk[k] >= 0) {
            int slot = atomicAdd(&cur[bk[k]], 1);
            rec[slot] = (unsigned)pk[k];
            bkt[slot] = (unsigned short)bk[k];
        }
    }
    __syncthreads();

    // coalesced flush: same-bucket slots contiguous in LDS AND in records[]
    for (int j = tid; j < total; j += 256) {
        int b  = bkt[j];
        int rk = gdelta[b] + j;        // rank within bucket's global region
        if ((unsigned)rk < (unsigned)BCAP)
            records[(size_t)b * BCAP + rk] = rec[j];
    }
}

// ---------------------------------------------------------------- Phase B
__global__ __launch_bounds__(256)
void occ_bucket2_kernel(const unsigned* __restrict__ records,
                        const unsigned* __restrict__ cursors,
                        const float*    __restrict__ grid,
                        float*          __restrict__ out) {
    __shared__ int smax[VOX_PER_BUCKET];    // 64 KB
    const int b   = blockIdx.x;
    const int tid = threadIdx.x;

    int4* s4 = reinterpret_cast<int4*>(smax);
    for (int j = tid; j < VOX_PER_BUCKET / 4; j += 256)
        s4[j] = make_int4(-1, -1, -1, -1);
    __syncthreads();

    const int cnt = (int)min(cursors[b], (unsigned)BCAP);
    const unsigned* rp  = records + (size_t)b * BCAP;
    const uint4*    rp4 = reinterpret_cast<const uint4*>(rp);
    const int quads = cnt >> 2;
    for (int j = tid; j < quads; j += 256) {
        uint4 e = rp4[j];                          // 4 records per 16B load
        atomicMax(&smax[e.x & (VOX_PER_BUCKET - 1)], (int)e.x);
        atomicMax(&smax[e.y & (VOX_PER_BUCKET - 1)], (int)e.y);
        atomicMax(&smax[e.z & (VOX_PER_BUCKET - 1)], (int)e.z);
        atomicMax(&smax[e.w & (VOX_PER_BUCKET - 1)], (int)e.w);
    }
    for (int j = quads * 4 + tid; j < cnt; j += 256) {
        unsigned e = rp[j];
        atomicMax(&smax[e & (VOX_PER_BUCKET - 1)], (int)e);
    }
    __syncthreads();

    // fused finalize: each voxel of this bucket written exactly once.
    // packed sign bit = occ sign = 0 -> packed >= 0 -> sentinel -1 unambiguous.
    const size_t vbase = (size_t)b * VOX_PER_BUCKET;
    const float4* g4  = reinterpret_cast<const float4*>(grid + vbase);
    float4*       o4  = reinterpret_cast<float4*>(out + vbase);
    const int4*   sm4 = reinterpret_cast<const int4*>(smax);
    for (int j = tid; j < VOX_PER_BUCKET / 4; j += 256) {
        int4   w = sm4[j];
        float4 g = g4[j];
        float4 r;
        r.x = (w.x == -1) ? g.x
            : fmaxf(EMA_DEC * g.x, __int_as_float(w.x & (int)0xFFFFC000));
        r.y = (w.y == -1) ? g.y
            : fmaxf(EMA_DEC * g.y, __int_as_float(w.y & (int)0xFFFFC000));
        r.z = (w.z == -1) ? g.z
            : fmaxf(EMA_DEC * g.z, __int_as_float(w.z & (int)0xFFFFC000));
        r.w = (w.w == -1) ? g.w
            : fmaxf(EMA_DEC * g.w, __int_as_float(w.w & (int)0xFFFFC000));
        o4[j] = r;
    }
}

// ------------------------------------------------- Fallback (proven R4 path)
__global__ void occ_scatter8_kernel(const float* __restrict__ pts,
                                    const float* __restrict__ occ_val,
                                    const int*   __restrict__ bidx,
                                    int*         __restrict__ out_bits,
                                    int n8, int n_total) {
    const int tid    = blockIdx.x * blockDim.x + threadIdx.x;
    const int stride = gridDim.x * blockDim.x;

    const float4* pts4 = reinterpret_cast<const float4*>(pts);
    const float4* ov4  = reinterpret_cast<const float4*>(occ_val);
    const int4*   bi4  = reinterpret_cast<const int4*>(bidx);

    for (int i = tid; i < n8; i += stride) {
        float4 q0 = pts4[i * 6 + 0];
        float4 q1 = pts4[i * 6 + 1];
        float4 q2 = pts4[i * 6 + 2];
        float4 q3 = pts4[i * 6 + 3];
        float4 q4 = pts4[i * 6 + 4];
        float4 q5 = pts4[i * 6 + 5];
        float4 oa = ov4[i * 2 + 0];
        float4 ob = ov4[i * 2 + 1];
        int4   ba = bi4[i * 2 + 0];
        int4   bb = bi4[i * 2 + 1];

        float xs[8] = {q0.x, q0.w, q1.z, q2.y, q3.x, q3.w, q4.z, q5.y};
        float ys[8] = {q0.y, q1.x, q1.w, q2.z, q3.y, q4.x, q4.w, q5.z};
        float zs[8] = {q0.z, q1.y, q2.x, q2.w, q3.z, q4.y, q5.x, q5.w};
        int   vb[8] = {__float_as_int(oa.x), __float_as_int(oa.y),
                       __float_as_int(oa.z), __float_as_int(oa.w),
                       __float_as_int(ob.x), __float_as_int(ob.y),
                       __float_as_int(ob.z), __float_as_int(ob.w)};
        int   bs[8] = {ba.x, ba.y, ba.z, ba.w, bb.x, bb.y, bb.z, bb.w};

        int idx[8];
        #pragma unroll
        for (int k = 0; k < 8; ++k) {
            int gx = quant_clamp(xs[k]);
            int gy = quant_clamp(ys[k]);
            int gz = quant_clamp(zs[k]);
            idx[k] = bs[k] * (GRID_R * GRID_R * GRID_R)
                   + gx * (GRID_R * GRID_R) + gy * GRID_R + gz;
        }
        #pragma unroll
        for (int k = 0; k < 8; ++k) atomicMax(&out_bits[idx[k]], vb[k]);
    }

    for (int i = n8 * 8 + tid; i < n_total; i += stride) {
        int gx = quant_clamp(pts[i * 3 + 0]);
        int gy = quant_clamp(pts[i * 3 + 1]);
        int gz = quant_clamp(pts[i * 3 + 2]);
        int idx = bidx[i] * (GRID_R * GRID_R * GRID_R)
                + gx * (GRID_R * GRID_R) + gy * GRID_R + gz;
        atomicMax(&out_bits[idx], __float_as_int(occ_val[i]));
    }
}

__global__ void occ_finalize_kernel(const float* __restrict__ grid,
                                    float*       __restrict__ out,
                                    int v4, int v_total) {
    const int tid    = blockIdx.x * blockDim.x + threadIdx.x;
    const int stride = gridDim.x * blockDim.x;

    const float4* g4 = reinterpret_cast<const float4*>(grid);
    int4*         w4 = reinterpret_cast<int4*>(out);
    float4*       o4 = reinterpret_cast<float4*>(out);

    for (int i = tid; i < v4; i += stride) {
        int4   w = w4[i];
        float4 g = g4[i];
        float4 r;
        r.x = (w.x == -1) ? g.x : fmaxf(EMA_DEC * g.x, __int_as_float(w.x));
        r.y = (w.y == -1) ? g.y : fmaxf(EMA_DEC * g.y, __int_as_float(w.y));
        r.z = (w.z == -1) ? g.z : fmaxf(EMA_DEC * g.z, __int_as_float(w.z));
        r.w = (w.w == -1) ? g.w : fmaxf(EMA_DEC * g.w, __int_as_float(w.w));
        o4[i] = r;
    }
    for (int i = v4 * 4 + tid; i < v_total; i += stride) {
        int w = reinterpret_cast<int*>(out)[i];
        float g = grid[i];
        out[i] = (w == -1) ? g : fmaxf(EMA_DEC * g, __int_as_float(w));
    }
}

// ---------------------------------------------------------------- launch
extern "C" void kernel_launch(void* const* d_in, const int* in_sizes, int n_in,
                              void* d_out, int out_size, void* d_ws, size_t ws_size,
                              hipStream_t stream) {
    const float* grid    = (const float*)d_in[0];   // (B,R,R,R) f32
    const float* pts     = (const float*)d_in[1];   // (N,3) f32
    const float* occ_val = (const float*)d_in[2];   // (N,) f32
    const int*   bidx    = (const int*)d_in[3];     // (N,) i32

    float* out = (float*)d_out;
    const int N = in_sizes[2];

    const size_t rec_bytes = (size_t)NBUCKET * BCAP * sizeof(unsigned); // ~21 MB
    const size_t need      = rec_bytes + NBUCKET * sizeof(unsigned);
    const bool shape_ok    = (out_size == 4 * GRID_R * GRID_R * GRID_R);

    if (ws_size >= need && shape_ok) {
        unsigned* records = (unsigned*)d_ws;
        unsigned* cursors = (unsigned*)((char*)d_ws + rec_bytes);

        hipMemsetAsync(cursors, 0, NBUCKET * sizeof(unsigned), stream);

        int pblocks = (N + PTS_PER_BLOCK - 1) / PTS_PER_BLOCK;
        if (pblocks < 1) pblocks = 1;
        occ_partition3_kernel<<<pblocks, 256, 0, stream>>>(
            pts, occ_val, bidx, records, cursors, N);

        occ_bucket2_kernel<<<NBUCKET, 256, 0, stream>>>(
            records, cursors, grid, out);
    } else {
        // fallback: sentinel memset + global atomic scatter + finalize
        hipMemsetAsync(d_out, 0xFF, (size_t)out_size * sizeof(float), stream);

        const int n8 = N / 8;
        int sblocks = (n8 + 255) / 256;
        if (sblocks < 1) sblocks = 1;
        occ_scatter8_kernel<<<sblocks, 256, 0, stream>>>(
            pts, occ_val, bidx, (int*)d_out, n8, N);

        const int v4 = out_size / 4;
        int fblocks = (v4 + 255) / 256;
        if (fblocks > 2048) fblocks = 2048;
        if (fblocks < 1) fblocks = 1;
        occ_finalize_kernel<<<fblocks, 256, 0, stream>>>(grid, out, v4, out_size);
    }
}

// Round 9
// 67.949 us; speedup vs baseline: 1.1034x; 1.1034x over previous
//
#include <hip/hip_runtime.h>
#include <hip/hip_bf16.h>

// OccupancyGridEMABatched:
//   out[v] = touched(v) ? max(0.95*grid[v], max_{pts at v} occ_val) : grid[v]
//
// R8 post-mortem: raising occupancy made partition SLOWER (53->58.7us) ->
// the wall is contention on the 512 global cursor words (262-524K atomicAdd
// on 2KB of memory; TCC same-line RMWs serialize). R9: ZERO global atomics.
// Deterministic counting sort:
//   A1: per-block 512-bucket LDS histogram -> H[blk][b]   (bucket=bidx*128+gx)
//   A2a: exclusive scan of H across blocks (one block/bucket) + totals T[b]
//   A2b: exclusive scan of T -> bucket starts S[513]
//   A3: R8 multisplit, reservations = S[b]+H[blk][b] READS (no atomics),
//       coalesced flush into dense sorted[N] at exact positions
//   B : one block per 16K-voxel bucket: LDS atomicMax of packed records +
//       fused finalize (out written exactly once; no memset needed)
// Packed 4B records: (val & 0xFFFFC000) | idx_low14 (18 value bits,
// err ~2^-8 << 2e-2 threshold). Fully deterministic, all passes BW-bound.

#define GRID_R          128
#define EMA_DEC         0.95f
#define NBUCKET         512           // 4 batches * 128 gx-planes
#define VOX_PER_BUCKET  16384         // 128*128 voxels = 64KB LDS
#define PTS_PER_BLOCK   4096
#define PTS_PER_THREAD  16            // 4096 / 256

__device__ __forceinline__ int quant_clamp(float p) {
    // ((p/2 + 0.5) * 128) truncated; *0.5 and *128 are exact pow2 scalings
    // (FMA contraction cannot change the result since p*0.5f is exact).
    int g = (int)((p * 0.5f + 0.5f) * (float)GRID_R);
    return min(max(g, 0), GRID_R - 1);
}

// ------------------------------------------------------------------ A1
__global__ __launch_bounds__(256)
void occ_hist_kernel(const float* __restrict__ pts,
                     const int*   __restrict__ bidx,
                     int*         __restrict__ H,      // [nblk][NBUCKET]
                     int n_total) {
    __shared__ int hist[NBUCKET];
    const int tid = threadIdx.x;
    for (int b = tid; b < NBUCKET; b += 256) hist[b] = 0;
    __syncthreads();

    const float4* pts4 = reinterpret_cast<const float4*>(pts);
    const int4*   bi4  = reinterpret_cast<const int4*>(bidx);

    #pragma unroll
    for (int r = 0; r < PTS_PER_THREAD / 8; ++r) {
        const int i = blockIdx.x * ((PTS_PER_THREAD / 8) * 256) + r * 256 + tid;
        if (i * 8 + 7 < n_total) {
            // bucket needs only x and bidx (bucket = bidx*128 + gx)
            float4 q0 = pts4[i * 6 + 0];
            float4 q1 = pts4[i * 6 + 1];
            float4 q2 = pts4[i * 6 + 2];
            float4 q3 = pts4[i * 6 + 3];
            float4 q4 = pts4[i * 6 + 4];
            float4 q5 = pts4[i * 6 + 5];
            int4   ba = bi4[i * 2 + 0];
            int4   bb = bi4[i * 2 + 1];
            float xs[8] = {q0.x, q0.w, q1.z, q2.y, q3.x, q3.w, q4.z, q5.y};
            int   bs[8] = {ba.x, ba.y, ba.z, ba.w, bb.x, bb.y, bb.z, bb.w};
            #pragma unroll
            for (int k = 0; k < 8; ++k)
                atomicAdd(&hist[bs[k] * (GRID_R >> 0 ? 128 : 128) + quant_clamp(xs[k])], 1);
        } else {
            #pragma unroll
            for (int k = 0; k < 8; ++k) {
                int p = i * 8 + k;
                if (p < n_total)
                    atomicAdd(&hist[bidx[p] * 128 + quant_clamp(pts[p * 3 + 0])], 1);
            }
        }
    }
    __syncthreads();
    for (int b = tid; b < NBUCKET; b += 256)
        H[(size_t)blockIdx.x * NBUCKET + b] = hist[b];   // coalesced
}

// ------------------------------------------------------------------ A2a
// One block per bucket: exclusive scan of H[k][b] over k, total -> T[b].
__global__ __launch_bounds__(256)
void occ_scan_blocks_kernel(int* __restrict__ H,
                            int* __restrict__ T,
                            int nblk) {
    __shared__ int wsum[4];
    const int b    = blockIdx.x;
    const int tid  = threadIdx.x;
    const int lane = tid & 63;
    const int wv   = tid >> 6;

    int carry = 0;
    for (int base = 0; base < nblk; base += 1024) {
        int v[4];
        #pragma unroll
        for (int j = 0; j < 4; ++j) {
            int k = base + tid * 4 + j;
            v[j] = (k < nblk) ? H[(size_t)k * NBUCKET + b] : 0;
        }
        int s = v[0] + v[1] + v[2] + v[3];
        int x = s;
        #pragma unroll
        for (int off = 1; off < 64; off <<= 1) {
            int t = __shfl_up(x, off, 64);
            if (lane >= off) x += t;
        }
        if (lane == 63) wsum[wv] = x;
        __syncthreads();
        const int w0 = wsum[0], w1 = wsum[1], w2 = wsum[2], w3 = wsum[3];
        const int wofs = (wv > 0 ? w0 : 0) + (wv > 1 ? w1 : 0) + (wv > 2 ? w2 : 0);
        const int tot  = w0 + w1 + w2 + w3;
        int run = carry + wofs + x - s;        // exclusive prefix for k=4t
        #pragma unroll
        for (int j = 0; j < 4; ++j) {
            int k = base + tid * 4 + j;
            if (k < nblk) { H[(size_t)k * NBUCKET + b] = run; run += v[j]; }
        }
        carry += tot;
        __syncthreads();                       // wsum reuse next chunk
    }
    if (tid == 0) T[b] = carry;
}

// ------------------------------------------------------------------ A2b
// Single block: exclusive scan of T[512] -> S[0..512] (S[512] = N_valid).
__global__ __launch_bounds__(256)
void occ_scan_buckets_kernel(const int* __restrict__ T,
                             int*       __restrict__ S) {
    __shared__ int wsum[4];
    const int tid  = threadIdx.x;
    const int lane = tid & 63;
    const int wv   = tid >> 6;

    const int a = T[2 * tid];
    const int c = T[2 * tid + 1];
    const int s = a + c;
    int x = s;
    #pragma unroll
    for (int off = 1; off < 64; off <<= 1) {
        int t = __shfl_up(x, off, 64);
        if (lane >= off) x += t;
    }
    if (lane == 63) wsum[wv] = x;
    __syncthreads();
    const int wofs = (wv > 0 ? wsum[0] : 0) + (wv > 1 ? wsum[1] : 0)
                   + (wv > 2 ? wsum[2] : 0);
    const int excl = x + wofs - s;
    S[2 * tid]     = excl;
    S[2 * tid + 1] = excl + a;
    if (tid == 255) S[NBUCKET] = excl + s;     // grand total
}

// ------------------------------------------------------------------ A3
__global__ __launch_bounds__(256)
void occ_place_kernel(const float* __restrict__ pts,
                      const float* __restrict__ occ_val,
                      const int*   __restrict__ bidx,
                      const int*   __restrict__ H,     // scanned [nblk][NBUCKET]
                      const int*   __restrict__ S,     // bucket starts [513]
                      unsigned*    __restrict__ sorted,
                      int n_total) {
    __shared__ unsigned       rec[PTS_PER_BLOCK];    // 16 KB (bucket-sorted)
    __shared__ unsigned short bkt[PTS_PER_BLOCK];    //  8 KB
    __shared__ int            cur[NBUCKET];          //  2 KB hist -> cursor
    __shared__ int            gdelta[NBUCKET];       //  2 KB gbase - scanExcl
    __shared__ int            wsum[4];

    const int tid  = threadIdx.x;
    const int lane = tid & 63;
    const int wv   = tid >> 6;

    for (int b = tid; b < NBUCKET; b += 256) cur[b] = 0;
    __syncthreads();

    const float4* pts4 = reinterpret_cast<const float4*>(pts);
    const float4* ov4  = reinterpret_cast<const float4*>(occ_val);
    const int4*   bi4  = reinterpret_cast<const int4*>(bidx);

    // statically-indexed -> stays in VGPRs (rule #20)
    int pk[PTS_PER_THREAD];
    int bk[PTS_PER_THREAD];

    #pragma unroll
    for (int r = 0; r < PTS_PER_THREAD / 8; ++r) {
        const int i = blockIdx.x * ((PTS_PER_THREAD / 8) * 256) + r * 256 + tid;
        if (i * 8 + 7 < n_total) {
            float4 q0 = pts4[i * 6 + 0];
            float4 q1 = pts4[i * 6 + 1];
            float4 q2 = pts4[i * 6 + 2];
            float4 q3 = pts4[i * 6 + 3];
            float4 q4 = pts4[i * 6 + 4];
            float4 q5 = pts4[i * 6 + 5];
            float4 oa = ov4[i * 2 + 0];
            float4 ob = ov4[i * 2 + 1];
            int4   ba = bi4[i * 2 + 0];
            int4   bb = bi4[i * 2 + 1];

            float xs[8] = {q0.x, q0.w, q1.z, q2.y, q3.x, q3.w, q4.z, q5.y};
            float ys[8] = {q0.y, q1.x, q1.w, q2.z, q3.y, q4.x, q4.w, q5.z};
            float zs[8] = {q0.z, q1.y, q2.x, q2.w, q3.z, q4.y, q5.x, q5.w};
            int   vb[8] = {__float_as_int(oa.x), __float_as_int(oa.y),
                           __float_as_int(oa.z), __float_as_int(oa.w),
                           __float_as_int(ob.x), __float_as_int(ob.y),
                           __float_as_int(ob.z), __float_as_int(ob.w)};
            int   bs[8] = {ba.x, ba.y, ba.z, ba.w, bb.x, bb.y, bb.z, bb.w};

            #pragma unroll
            for (int k = 0; k < 8; ++k) {
                int gx = quant_clamp(xs[k]);
                int gy = quant_clamp(ys[k]);
                int gz = quant_clamp(zs[k]);
                int idx = bs[k] * (GRID_R * GRID_R * GRID_R)
                        + gx * (GRID_R * GRID_R) + gy * GRID_R + gz;
                pk[r * 8 + k] = (vb[k] & (int)0xFFFFC000) | (idx & 0x3FFF);
                bk[r * 8 + k] = idx >> 14;
            }
        } else {
            #pragma unroll
            for (int k = 0; k < 8; ++k) {
                bk[r * 8 + k] = -1;
                pk[r * 8 + k] = 0;
                int p = i * 8 + k;
                if (p < n_total) {
                    int gx = quant_clamp(pts[p * 3 + 0]);
                    int gy = quant_clamp(pts[p * 3 + 1]);
                    int gz = quant_clamp(pts[p * 3 + 2]);
                    int idx = bidx[p] * (GRID_R * GRID_R * GRID_R)
                            + gx * (GRID_R * GRID_R) + gy * GRID_R + gz;
                    pk[r * 8 + k] = (__float_as_int(occ_val[p]) & (int)0xFFFFC000)
                                  | (idx & 0x3FFF);
                    bk[r * 8 + k] = idx >> 14;
                }
            }
        }
    }

    // block-local histogram
    #pragma unroll
    for (int k = 0; k < PTS_PER_THREAD; ++k)
        if (bk[k] >= 0) atomicAdd(&cur[bk[k]], 1);
    __syncthreads();

    // thread t owns buckets {2t, 2t+1}
    const int a = cur[2 * tid];
    const int c = cur[2 * tid + 1];
    const int s = a + c;

    // exact global bases: S[b] + H_scanned[blk][b]  (plain reads, L2-hot)
    const int2 Sp = *reinterpret_cast<const int2*>(&S[2 * tid]);
    const int2 Hp = *reinterpret_cast<const int2*>(
                        &H[(size_t)blockIdx.x * NBUCKET + 2 * tid]);
    const int g0 = Sp.x + Hp.x;
    const int g1 = Sp.y + Hp.y;

    // wave-level inclusive scan of s for the LDS layout (load latency hides)
    int x = s;
    #pragma unroll
    for (int off = 1; off < 64; off <<= 1) {
        int v = __shfl_up(x, off, 64);
        if (lane >= off) x += v;
    }
    if (lane == 63) wsum[wv] = x;
    __syncthreads();

    const int w0 = wsum[0], w1 = wsum[1], w2 = wsum[2], w3 = wsum[3];
    const int wofs  = (wv > 0 ? w0 : 0) + (wv > 1 ? w1 : 0) + (wv > 2 ? w2 : 0);
    const int total = w0 + w1 + w2 + w3;
    const int excl  = x + wofs - s;     // exclusive prefix of bucket 2t

    cur[2 * tid]        = excl;
    cur[2 * tid + 1]    = excl + a;
    gdelta[2 * tid]     = g0 - excl;
    gdelta[2 * tid + 1] = g1 - (excl + a);
    __syncthreads();

    // bucket-sort records into LDS
    #pragma unroll
    for (int k = 0; k < PTS_PER_THREAD; ++k) {
        if (bk[k] >= 0) {
            int slot = atomicAdd(&cur[bk[k]], 1);
            rec[slot] = (unsigned)pk[k];
            bkt[slot] = (unsigned short)bk[k];
        }
    }
    __syncthreads();

    // coalesced flush at EXACT positions (no capacity clamp needed)
    for (int j = tid; j < total; j += 256) {
        int b = bkt[j];
        sorted[gdelta[b] + j] = rec[j];
    }
}

// ------------------------------------------------------------------ B
__global__ __launch_bounds__(256)
void occ_bucket3_kernel(const unsigned* __restrict__ sorted,
                        const int*      __restrict__ S,
                        const float*    __restrict__ grid,
                        float*          __restrict__ out) {
    __shared__ int smax[VOX_PER_BUCKET];    // 64 KB
    const int b   = blockIdx.x;
    const int tid = threadIdx.x;

    int4* s4 = reinterpret_cast<int4*>(smax);
    for (int j = tid; j < VOX_PER_BUCKET / 4; j += 256)
        s4[j] = make_int4(-1, -1, -1, -1);
    __syncthreads();

    const int s0  = S[b];
    const int cnt = S[b + 1] - s0;
    const unsigned* rp = sorted + s0;

    // head scalars until 16B-aligned, uint4 body, tail scalars
    const int head = min(cnt, (int)((4 - (((unsigned)(size_t)rp >> 2) & 3)) & 3));
    for (int j = tid; j < head; j += 256) {
        unsigned e = rp[j];
        atomicMax(&smax[e & (VOX_PER_BUCKET - 1)], (int)e);
    }
    const int body4 = (cnt - head) >> 2;
    const uint4* rp4 = reinterpret_cast<const uint4*>(rp + head);
    for (int j = tid; j < body4; j += 256) {
        uint4 e = rp4[j];
        atomicMax(&smax[e.x & (VOX_PER_BUCKET - 1)], (int)e.x);
        atomicMax(&smax[e.y & (VOX_PER_BUCKET - 1)], (int)e.y);
        atomicMax(&smax[e.z & (VOX_PER_BUCKET - 1)], (int)e.z);
        atomicMax(&smax[e.w & (VOX_PER_BUCKET - 1)], (int)e.w);
    }
    for (int j = head + body4 * 4 + tid; j < cnt; j += 256) {
        unsigned e = rp[j];
        atomicMax(&smax[e & (VOX_PER_BUCKET - 1)], (int)e);
    }
    __syncthreads();

    // fused finalize: each voxel written exactly once.
    // packed sign bit = occ sign = 0 -> packed >= 0 -> sentinel -1 unambiguous.
    const size_t vbase = (size_t)b * VOX_PER_BUCKET;
    const float4* g4  = reinterpret_cast<const float4*>(grid + vbase);
    float4*       o4  = reinterpret_cast<float4*>(out + vbase);
    const int4*   sm4 = reinterpret_cast<const int4*>(smax);
    for (int j = tid; j < VOX_PER_BUCKET / 4; j += 256) {
        int4   w = sm4[j];
        float4 g = g4[j];
        float4 r;
        r.x = (w.x == -1) ? g.x
            : fmaxf(EMA_DEC * g.x, __int_as_float(w.x & (int)0xFFFFC000));
        r.y = (w.y == -1) ? g.y
            : fmaxf(EMA_DEC * g.y, __int_as_float(w.y & (int)0xFFFFC000));
        r.z = (w.z == -1) ? g.z
            : fmaxf(EMA_DEC * g.z, __int_as_float(w.z & (int)0xFFFFC000));
        r.w = (w.w == -1) ? g.w
            : fmaxf(EMA_DEC * g.w, __int_as_float(w.w & (int)0xFFFFC000));
        o4[j] = r;
    }
}

// ------------------------------------------------- Fallback (proven R4 path)
__global__ void occ_scatter8_kernel(const float* __restrict__ pts,
                                    const float* __restrict__ occ_val,
                                    const int*   __restrict__ bidx,
                                    int*         __restrict__ out_bits,
                                    int n8, int n_total) {
    const int tid    = blockIdx.x * blockDim.x + threadIdx.x;
    const int stride = gridDim.x * blockDim.x;

    const float4* pts4 = reinterpret_cast<const float4*>(pts);
    const float4* ov4  = reinterpret_cast<const float4*>(occ_val);
    const int4*   bi4  = reinterpret_cast<const int4*>(bidx);

    for (int i = tid; i < n8; i += stride) {
        float4 q0 = pts4[i * 6 + 0];
        float4 q1 = pts4[i * 6 + 1];
        float4 q2 = pts4[i * 6 + 2];
        float4 q3 = pts4[i * 6 + 3];
        float4 q4 = pts4[i * 6 + 4];
        float4 q5 = pts4[i * 6 + 5];
        float4 oa = ov4[i * 2 + 0];
        float4 ob = ov4[i * 2 + 1];
        int4   ba = bi4[i * 2 + 0];
        int4   bb = bi4[i * 2 + 1];

        float xs[8] = {q0.x, q0.w, q1.z, q2.y, q3.x, q3.w, q4.z, q5.y};
        float ys[8] = {q0.y, q1.x, q1.w, q2.z, q3.y, q4.x, q4.w, q5.z};
        float zs[8] = {q0.z, q1.y, q2.x, q2.w, q3.z, q4.y, q5.x, q5.w};
        int   vb[8] = {__float_as_int(oa.x), __float_as_int(oa.y),
                       __float_as_int(oa.z), __float_as_int(oa.w),
                       __float_as_int(ob.x), __float_as_int(ob.y),
                       __float_as_int(ob.z), __float_as_int(ob.w)};
        int   bs[8] = {ba.x, ba.y, ba.z, ba.w, bb.x, bb.y, bb.z, bb.w};

        int idx[8];
        #pragma unroll
        for (int k = 0; k < 8; ++k) {
            int gx = quant_clamp(xs[k]);
            int gy = quant_clamp(ys[k]);
            int gz = quant_clamp(zs[k]);
            idx[k] = bs[k] * (GRID_R * GRID_R * GRID_R)
                   + gx * (GRID_R * GRID_R) + gy * GRID_R + gz;
        }
        #pragma unroll
        for (int k = 0; k < 8; ++k) atomicMax(&out_bits[idx[k]], vb[k]);
    }

    for (int i = n8 * 8 + tid; i < n_total; i += stride) {
        int gx = quant_clamp(pts[i * 3 + 0]);
        int gy = quant_clamp(pts[i * 3 + 1]);
        int gz = quant_clamp(pts[i * 3 + 2]);
        int idx = bidx[i] * (GRID_R * GRID_R * GRID_R)
                + gx * (GRID_R * GRID_R) + gy * GRID_R + gz;
        atomicMax(&out_bits[idx], __float_as_int(occ_val[i]));
    }
}

__global__ void occ_finalize_kernel(const float* __restrict__ grid,
                                    float*       __restrict__ out,
                                    int v4, int v_total) {
    const int tid    = blockIdx.x * blockDim.x + threadIdx.x;
    const int stride = gridDim.x * blockDim.x;

    const float4* g4 = reinterpret_cast<const float4*>(grid);
    int4*         w4 = reinterpret_cast<int4*>(out);
    float4*       o4 = reinterpret_cast<float4*>(out);

    for (int i = tid; i < v4; i += stride) {
        int4   w = w4[i];
        float4 g = g4[i];
        float4 r;
        r.x = (w.x == -1) ? g.x : fmaxf(EMA_DEC * g.x, __int_as_float(w.x));
        r.y = (w.y == -1) ? g.y : fmaxf(EMA_DEC * g.y, __int_as_float(w.y));
        r.z = (w.z == -1) ? g.z : fmaxf(EMA_DEC * g.z, __int_as_float(w.z));
        r.w = (w.w == -1) ? g.w : fmaxf(EMA_DEC * g.w, __int_as_float(w.w));
        o4[i] = r;
    }
    for (int i = v4 * 4 + tid; i < v_total; i += stride) {
        int w = reinterpret_cast<int*>(out)[i];
        float g = grid[i];
        out[i] = (w == -1) ? g : fmaxf(EMA_DEC * g, __int_as_float(w));
    }
}

// ---------------------------------------------------------------- launch
extern "C" void kernel_launch(void* const* d_in, const int* in_sizes, int n_in,
                              void* d_out, int out_size, void* d_ws, size_t ws_size,
                              hipStream_t stream) {
    const float* grid    = (const float*)d_in[0];   // (B,R,R,R) f32
    const float* pts     = (const float*)d_in[1];   // (N,3) f32
    const float* occ_val = (const float*)d_in[2];   // (N,) f32
    const int*   bidx    = (const int*)d_in[3];     // (N,) i32

    float* out = (float*)d_out;
    const int N = in_sizes[2];

    const int nblk = (N + PTS_PER_BLOCK - 1) / PTS_PER_BLOCK;

    // ws layout: sorted[N] | H[nblk][512] | T[512] | S[513]
    const size_t sorted_b = (size_t)N * sizeof(unsigned);
    const size_t h_b      = (size_t)nblk * NBUCKET * sizeof(int);
    const size_t need     = sorted_b + h_b + (NBUCKET + NBUCKET + 1) * sizeof(int);
    const bool shape_ok   = (out_size == 4 * GRID_R * GRID_R * GRID_R);

    if (ws_size >= need && shape_ok && nblk >= 1) {
        unsigned* sorted = (unsigned*)d_ws;
        int*      H      = (int*)((char*)d_ws + sorted_b);
        int*      T      = (int*)((char*)d_ws + sorted_b + h_b);
        int*      S      = T + NBUCKET;

        occ_hist_kernel<<<nblk, 256, 0, stream>>>(pts, bidx, H, N);
        occ_scan_blocks_kernel<<<NBUCKET, 256, 0, stream>>>(H, T, nblk);
        occ_scan_buckets_kernel<<<1, 256, 0, stream>>>(T, S);
        occ_place_kernel<<<nblk, 256, 0, stream>>>(
            pts, occ_val, bidx, H, S, sorted, N);
        occ_bucket3_kernel<<<NBUCKET, 256, 0, stream>>>(sorted, S, grid, out);
    } else {
        // fallback: sentinel memset + global atomic scatter + finalize
        hipMemsetAsync(d_out, 0xFF, (size_t)out_size * sizeof(float), stream);

        const int n8 = N / 8;
        int sblocks = (n8 + 255) / 256;
        if (sblocks < 1) sblocks = 1;
        occ_scatter8_kernel<<<sblocks, 256, 0, stream>>>(
            pts, occ_val, bidx, (int*)d_out, n8, N);

        const int v4 = out_size / 4;
        int fblocks = (v4 + 255) / 256;
        if (fblocks > 2048) fblocks = 2048;
        if (fblocks < 1) fblocks = 1;
        occ_finalize_kernel<<<fblocks, 256, 0, stream>>>(grid, out, v4, out_size);
    }
}

// Round 10
// 55.612 us; speedup vs baseline: 1.3482x; 1.2218x over previous
//
#include <hip/hip_runtime.h>
#include <hip/hip_bf16.h>

// OccupancyGridEMABatched:
//   out[v] = touched(v) ? max(0.95*grid[v], max_{pts at v} occ_val) : grid[v]
//
// R9 post-mortem: counting sort (5 kernels) = 67.9us vs ~30us floor; the gap
// is cross-block coupling overhead (2nd pts read, strided H scan, 5 launch
// gaps). R10: block-LOCAL grouping, zero cross-block communication:
//   K1: each block multisplits its 4096 pts into a DENSE per-chunk segment
//       sorted[c*4096..] (records grouped by bucket within the chunk) and
//       writes offT[513][nchunk] (u16 transposed per-chunk bucket offsets).
//       One pts read. No global scan/cursors/sync.
//   K2: one block per bucket b (XCD-chunk-swizzled so adjacent buckets share
//       an XCD L2 for the partial-line slice reads): read offT rows b,b+1
//       (coalesced), gather per-chunk slices, LDS atomicMax of packed
//       records, fused finalize (out written exactly once; no memset).
// Packed 4B records: (val & 0xFFFFC000) | idx_low14 (18 value bits,
// err ~2^-8 << 2e-2 threshold). Deterministic: per-voxel max is
// order-insensitive to record order.

#define GRID_R          128
#define EMA_DEC         0.95f
#define NBUCKET         512           // 4 batches * 128 gx-planes
#define VOX_PER_BUCKET  16384         // 128*128 voxels = 64KB LDS
#define PTS_PER_BLOCK   4096
#define PTS_PER_THREAD  16            // 4096 / 256

__device__ __forceinline__ int quant_clamp(float p) {
    // ((p/2 + 0.5) * 128) truncated; *0.5 and *128 are exact pow2 scalings
    // (FMA contraction cannot change the result since p*0.5f is exact).
    int g = (int)((p * 0.5f + 0.5f) * (float)GRID_R);
    return min(max(g, 0), GRID_R - 1);
}

// ------------------------------------------------------------------ K1
// Block-local multisplit: 4096 pts -> bucket-grouped dense chunk segment
// + transposed u16 offset table. No cross-block anything.
__global__ __launch_bounds__(256)
void occ_localsort_kernel(const float* __restrict__ pts,
                          const float* __restrict__ occ_val,
                          const int*   __restrict__ bidx,
                          unsigned*        __restrict__ sorted,  // [nchunk*4096]
                          unsigned short*  __restrict__ offT,    // [513][nchunk]
                          int n_total, int nchunk) {
    __shared__ unsigned rec[PTS_PER_BLOCK];   // 16 KB (bucket-grouped)
    __shared__ int      cur[NBUCKET];         //  2 KB hist -> cursor
    __shared__ int      wsum[4];

    const int tid  = threadIdx.x;
    const int lane = tid & 63;
    const int wv   = tid >> 6;
    const int c    = blockIdx.x;              // chunk id

    for (int b = tid; b < NBUCKET; b += 256) cur[b] = 0;
    __syncthreads();

    const float4* pts4 = reinterpret_cast<const float4*>(pts);
    const float4* ov4  = reinterpret_cast<const float4*>(occ_val);
    const int4*   bi4  = reinterpret_cast<const int4*>(bidx);

    // statically-indexed -> stays in VGPRs (rule #20)
    int pk[PTS_PER_THREAD];
    int bk[PTS_PER_THREAD];

    #pragma unroll
    for (int r = 0; r < PTS_PER_THREAD / 8; ++r) {
        // 8-point group id; block owns groups [c*512, c*512+512)
        const int i = c * ((PTS_PER_THREAD / 8) * 256) + r * 256 + tid;
        if (i * 8 + 7 < n_total) {
            float4 q0 = pts4[i * 6 + 0];
            float4 q1 = pts4[i * 6 + 1];
            float4 q2 = pts4[i * 6 + 2];
            float4 q3 = pts4[i * 6 + 3];
            float4 q4 = pts4[i * 6 + 4];
            float4 q5 = pts4[i * 6 + 5];
            float4 oa = ov4[i * 2 + 0];
            float4 ob = ov4[i * 2 + 1];
            int4   ba = bi4[i * 2 + 0];
            int4   bb = bi4[i * 2 + 1];

            float xs[8] = {q0.x, q0.w, q1.z, q2.y, q3.x, q3.w, q4.z, q5.y};
            float ys[8] = {q0.y, q1.x, q1.w, q2.z, q3.y, q4.x, q4.w, q5.z};
            float zs[8] = {q0.z, q1.y, q2.x, q2.w, q3.z, q4.y, q5.x, q5.w};
            int   vb[8] = {__float_as_int(oa.x), __float_as_int(oa.y),
                           __float_as_int(oa.z), __float_as_int(oa.w),
                           __float_as_int(ob.x), __float_as_int(ob.y),
                           __float_as_int(ob.z), __float_as_int(ob.w)};
            int   bs[8] = {ba.x, ba.y, ba.z, ba.w, bb.x, bb.y, bb.z, bb.w};

            #pragma unroll
            for (int k = 0; k < 8; ++k) {
                int gx = quant_clamp(xs[k]);
                int gy = quant_clamp(ys[k]);
                int gz = quant_clamp(zs[k]);
                int idx = bs[k] * (GRID_R * GRID_R * GRID_R)
                        + gx * (GRID_R * GRID_R) + gy * GRID_R + gz;
                pk[r * 8 + k] = (vb[k] & (int)0xFFFFC000) | (idx & 0x3FFF);
                bk[r * 8 + k] = idx >> 14;
            }
        } else {
            #pragma unroll
            for (int k = 0; k < 8; ++k) {
                bk[r * 8 + k] = -1;
                pk[r * 8 + k] = 0;
                int p = i * 8 + k;
                if (p < n_total) {
                    int gx = quant_clamp(pts[p * 3 + 0]);
                    int gy = quant_clamp(pts[p * 3 + 1]);
                    int gz = quant_clamp(pts[p * 3 + 2]);
                    int idx = bidx[p] * (GRID_R * GRID_R * GRID_R)
                            + gx * (GRID_R * GRID_R) + gy * GRID_R + gz;
                    pk[r * 8 + k] = (__float_as_int(occ_val[p]) & (int)0xFFFFC000)
                                  | (idx & 0x3FFF);
                    bk[r * 8 + k] = idx >> 14;
                }
            }
        }
    }

    // block-local histogram
    #pragma unroll
    for (int k = 0; k < PTS_PER_THREAD; ++k)
        if (bk[k] >= 0) atomicAdd(&cur[bk[k]], 1);
    __syncthreads();

    // thread t owns buckets {2t, 2t+1}; wave scan of pair-sums
    const int a = cur[2 * tid];
    const int cc = cur[2 * tid + 1];
    const int s = a + cc;
    int x = s;
    #pragma unroll
    for (int off = 1; off < 64; off <<= 1) {
        int v = __shfl_up(x, off, 64);
        if (lane >= off) x += v;
    }
    if (lane == 63) wsum[wv] = x;
    __syncthreads();

    const int w0 = wsum[0], w1 = wsum[1], w2 = wsum[2], w3 = wsum[3];
    const int wofs  = (wv > 0 ? w0 : 0) + (wv > 1 ? w1 : 0) + (wv > 2 ? w2 : 0);
    const int total = w0 + w1 + w2 + w3;
    const int excl  = x + wofs - s;     // exclusive prefix of bucket 2t

    // per-chunk offset table (transposed: row = bucket, col = chunk)
    offT[(size_t)(2 * tid)     * nchunk + c] = (unsigned short)excl;
    offT[(size_t)(2 * tid + 1) * nchunk + c] = (unsigned short)(excl + a);
    if (tid == 255)
        offT[(size_t)NBUCKET   * nchunk + c] = (unsigned short)total;

    cur[2 * tid]     = excl;
    cur[2 * tid + 1] = excl + a;
    __syncthreads();

    // multisplit into LDS (grouped by bucket)
    #pragma unroll
    for (int k = 0; k < PTS_PER_THREAD; ++k) {
        if (bk[k] >= 0) {
            int slot = atomicAdd(&cur[bk[k]], 1);
            rec[slot] = (unsigned)pk[k];
        }
    }
    __syncthreads();

    // dense, perfectly coalesced flush into this chunk's segment
    unsigned* dst = sorted + (size_t)c * PTS_PER_BLOCK;
    for (int j = tid; j < total; j += 256)
        dst[j] = rec[j];
}

// ------------------------------------------------------------------ K2
// One block per bucket: gather per-chunk slices, LDS max, fused finalize.
__global__ __launch_bounds__(256)
void occ_bucket4_kernel(const unsigned*       __restrict__ sorted,
                        const unsigned short* __restrict__ offT,
                        const float*          __restrict__ grid,
                        float*                __restrict__ out,
                        int nchunk) {
    __shared__ int smax[VOX_PER_BUCKET];    // 64 KB
    const int tid = threadIdx.x;
    // XCD-chunked bucket assignment: adjacent logical buckets land on the
    // same XCD -> shared L2 lines for slice reads (512 = 8*64, bijective).
    const int b = (blockIdx.x & 7) * (NBUCKET / 8) + (blockIdx.x >> 3);

    int4* s4 = reinterpret_cast<int4*>(smax);
    for (int j = tid; j < VOX_PER_BUCKET / 4; j += 256)
        s4[j] = make_int4(-1, -1, -1, -1);
    __syncthreads();

    const unsigned short* rowLo = offT + (size_t)b       * nchunk;
    const unsigned short* rowHi = offT + (size_t)(b + 1) * nchunk;

    // threads stride chunks; slice reads are small but MLP-rich
    for (int c = tid; c < nchunk; c += 256) {
        const int lo = rowLo[c];
        const int hi = rowHi[c];
        const unsigned* rp = sorted + (size_t)c * PTS_PER_BLOCK;
        for (int j = lo; j < hi; ++j) {
            unsigned e = rp[j];
            atomicMax(&smax[e & (VOX_PER_BUCKET - 1)], (int)e);
        }
    }
    __syncthreads();

    // fused finalize: each voxel of this bucket written exactly once.
    // packed sign bit = occ sign = 0 -> packed >= 0 -> sentinel -1 unambiguous.
    const size_t vbase = (size_t)b * VOX_PER_BUCKET;
    const float4* g4  = reinterpret_cast<const float4*>(grid + vbase);
    float4*       o4  = reinterpret_cast<float4*>(out + vbase);
    const int4*   sm4 = reinterpret_cast<const int4*>(smax);
    for (int j = tid; j < VOX_PER_BUCKET / 4; j += 256) {
        int4   w = sm4[j];
        float4 g = g4[j];
        float4 r;
        r.x = (w.x == -1) ? g.x
            : fmaxf(EMA_DEC * g.x, __int_as_float(w.x & (int)0xFFFFC000));
        r.y = (w.y == -1) ? g.y
            : fmaxf(EMA_DEC * g.y, __int_as_float(w.y & (int)0xFFFFC000));
        r.z = (w.z == -1) ? g.z
            : fmaxf(EMA_DEC * g.z, __int_as_float(w.z & (int)0xFFFFC000));
        r.w = (w.w == -1) ? g.w
            : fmaxf(EMA_DEC * g.w, __int_as_float(w.w & (int)0xFFFFC000));
        o4[j] = r;
    }
}

// ------------------------------------------------- Fallback (proven R4 path)
__global__ void occ_scatter8_kernel(const float* __restrict__ pts,
                                    const float* __restrict__ occ_val,
                                    const int*   __restrict__ bidx,
                                    int*         __restrict__ out_bits,
                                    int n8, int n_total) {
    const int tid    = blockIdx.x * blockDim.x + threadIdx.x;
    const int stride = gridDim.x * blockDim.x;

    const float4* pts4 = reinterpret_cast<const float4*>(pts);
    const float4* ov4  = reinterpret_cast<const float4*>(occ_val);
    const int4*   bi4  = reinterpret_cast<const int4*>(bidx);

    for (int i = tid; i < n8; i += stride) {
        float4 q0 = pts4[i * 6 + 0];
        float4 q1 = pts4[i * 6 + 1];
        float4 q2 = pts4[i * 6 + 2];
        float4 q3 = pts4[i * 6 + 3];
        float4 q4 = pts4[i * 6 + 4];
        float4 q5 = pts4[i * 6 + 5];
        float4 oa = ov4[i * 2 + 0];
        float4 ob = ov4[i * 2 + 1];
        int4   ba = bi4[i * 2 + 0];
        int4   bb = bi4[i * 2 + 1];

        float xs[8] = {q0.x, q0.w, q1.z, q2.y, q3.x, q3.w, q4.z, q5.y};
        float ys[8] = {q0.y, q1.x, q1.w, q2.z, q3.y, q4.x, q4.w, q5.z};
        float zs[8] = {q0.z, q1.y, q2.x, q2.w, q3.z, q4.y, q5.x, q5.w};
        int   vb[8] = {__float_as_int(oa.x), __float_as_int(oa.y),
                       __float_as_int(oa.z), __float_as_int(oa.w),
                       __float_as_int(ob.x), __float_as_int(ob.y),
                       __float_as_int(ob.z), __float_as_int(ob.w)};
        int   bs[8] = {ba.x, ba.y, ba.z, ba.w, bb.x, bb.y, bb.z, bb.w};

        int idx[8];
        #pragma unroll
        for (int k = 0; k < 8; ++k) {
            int gx = quant_clamp(xs[k]);
            int gy = quant_clamp(ys[k]);
            int gz = quant_clamp(zs[k]);
            idx[k] = bs[k] * (GRID_R * GRID_R * GRID_R)
                   + gx * (GRID_R * GRID_R) + gy * GRID_R + gz;
        }
        #pragma unroll
        for (int k = 0; k < 8; ++k) atomicMax(&out_bits[idx[k]], vb[k]);
    }

    for (int i = n8 * 8 + tid; i < n_total; i += stride) {
        int gx = quant_clamp(pts[i * 3 + 0]);
        int gy = quant_clamp(pts[i * 3 + 1]);
        int gz = quant_clamp(pts[i * 3 + 2]);
        int idx = bidx[i] * (GRID_R * GRID_R * GRID_R)
                + gx * (GRID_R * GRID_R) + gy * GRID_R + gz;
        atomicMax(&out_bits[idx], __float_as_int(occ_val[i]));
    }
}

__global__ void occ_finalize_kernel(const float* __restrict__ grid,
                                    float*       __restrict__ out,
                                    int v4, int v_total) {
    const int tid    = blockIdx.x * blockDim.x + threadIdx.x;
    const int stride = gridDim.x * blockDim.x;

    const float4* g4 = reinterpret_cast<const float4*>(grid);
    int4*         w4 = reinterpret_cast<int4*>(out);
    float4*       o4 = reinterpret_cast<float4*>(out);

    for (int i = tid; i < v4; i += stride) {
        int4   w = w4[i];
        float4 g = g4[i];
        float4 r;
        r.x = (w.x == -1) ? g.x : fmaxf(EMA_DEC * g.x, __int_as_float(w.x));
        r.y = (w.y == -1) ? g.y : fmaxf(EMA_DEC * g.y, __int_as_float(w.y));
        r.z = (w.z == -1) ? g.z : fmaxf(EMA_DEC * g.z, __int_as_float(w.z));
        r.w = (w.w == -1) ? g.w : fmaxf(EMA_DEC * g.w, __int_as_float(w.w));
        o4[i] = r;
    }
    for (int i = v4 * 4 + tid; i < v_total; i += stride) {
        int w = reinterpret_cast<int*>(out)[i];
        float g = grid[i];
        out[i] = (w == -1) ? g : fmaxf(EMA_DEC * g, __int_as_float(w));
    }
}

// ---------------------------------------------------------------- launch
extern "C" void kernel_launch(void* const* d_in, const int* in_sizes, int n_in,
                              void* d_out, int out_size, void* d_ws, size_t ws_size,
                              hipStream_t stream) {
    const float* grid    = (const float*)d_in[0];   // (B,R,R,R) f32
    const float* pts     = (const float*)d_in[1];   // (N,3) f32
    const float* occ_val = (const float*)d_in[2];   // (N,) f32
    const int*   bidx    = (const int*)d_in[3];     // (N,) i32

    float* out = (float*)d_out;
    const int N = in_sizes[2];

    const int nchunk = (N + PTS_PER_BLOCK - 1) / PTS_PER_BLOCK;

    // ws layout: sorted[nchunk*4096] u32 | offT[513][nchunk] u16
    const size_t sorted_b = (size_t)nchunk * PTS_PER_BLOCK * sizeof(unsigned);
    const size_t off_b    = (size_t)(NBUCKET + 1) * nchunk * sizeof(unsigned short);
    const size_t need     = sorted_b + off_b;
    const bool shape_ok   = (out_size == 4 * GRID_R * GRID_R * GRID_R);

    if (ws_size >= need && shape_ok && nchunk >= 1) {
        unsigned*       sorted = (unsigned*)d_ws;
        unsigned short* offT   = (unsigned short*)((char*)d_ws + sorted_b);

        occ_localsort_kernel<<<nchunk, 256, 0, stream>>>(
            pts, occ_val, bidx, sorted, offT, N, nchunk);
        occ_bucket4_kernel<<<NBUCKET, 256, 0, stream>>>(
            sorted, offT, grid, out, nchunk);
    } else {
        // fallback: sentinel memset + global atomic scatter + finalize
        hipMemsetAsync(d_out, 0xFF, (size_t)out_size * sizeof(float), stream);

        const int n8 = N / 8;
        int sblocks = (n8 + 255) / 256;
        if (sblocks < 1) sblocks = 1;
        occ_scatter8_kernel<<<sblocks, 256, 0, stream>>>(
            pts, occ_val, bidx, (int*)d_out, n8, N);

        const int v4 = out_size / 4;
        int fblocks = (v4 + 255) / 256;
        if (fblocks > 2048) fblocks = 2048;
        if (fblocks < 1) fblocks = 1;
        occ_finalize_kernel<<<fblocks, 256, 0, stream>>>(grid, out, v4, out_size);
    }
}

// Round 11
// 43.781 us; speedup vs baseline: 1.7126x; 1.2702x over previous
//
#include <hip/hip_runtime.h>
#include <hip/hip_bf16.h>

// OccupancyGridEMABatched:
//   out[v] = touched(v) ? max(0.95*grid[v], max_{pts at v} occ_val) : grid[v]
//
// R10 post-mortem: K1 localsort ~12us (floor); K2 gather ~43us, latency-bound
// (serial scalar slice loads, dynamic-bound loop, 8 waves/CU, 17% HBM).
// R11: K2 gather restructured:
//   * uint4 vectorized slice reads (lo&~3 .. hi, per-element masking):
//     4x fewer loads, 4 independent LDS atomics per load
//   * 512 threads/block: 16 waves/CU latency hiding, half the serial depth
// K1 unchanged (block-local multisplit -> dense chunk segment + u16 offT).
// Packed 4B records: (val & 0xFFFFC000) | idx_low14 (18 value bits,
// err ~2^-8 << 2e-2 threshold). Deterministic: per-voxel max is
// order-insensitive to record order.

#define GRID_R          128
#define EMA_DEC         0.95f
#define NBUCKET         512           // 4 batches * 128 gx-planes
#define VOX_PER_BUCKET  16384         // 128*128 voxels = 64KB LDS
#define PTS_PER_BLOCK   4096
#define PTS_PER_THREAD  16            // 4096 / 256

__device__ __forceinline__ int quant_clamp(float p) {
    // ((p/2 + 0.5) * 128) truncated; *0.5 and *128 are exact pow2 scalings
    // (FMA contraction cannot change the result since p*0.5f is exact).
    int g = (int)((p * 0.5f + 0.5f) * (float)GRID_R);
    return min(max(g, 0), GRID_R - 1);
}

// ------------------------------------------------------------------ K1
// Block-local multisplit: 4096 pts -> bucket-grouped dense chunk segment
// + transposed u16 offset table. No cross-block anything.
__global__ __launch_bounds__(256)
void occ_localsort_kernel(const float* __restrict__ pts,
                          const float* __restrict__ occ_val,
                          const int*   __restrict__ bidx,
                          unsigned*        __restrict__ sorted,  // [nchunk*4096]
                          unsigned short*  __restrict__ offT,    // [513][nchunk]
                          int n_total, int nchunk) {
    __shared__ unsigned rec[PTS_PER_BLOCK];   // 16 KB (bucket-grouped)
    __shared__ int      cur[NBUCKET];         //  2 KB hist -> cursor
    __shared__ int      wsum[4];

    const int tid  = threadIdx.x;
    const int lane = tid & 63;
    const int wv   = tid >> 6;
    const int c    = blockIdx.x;              // chunk id

    for (int b = tid; b < NBUCKET; b += 256) cur[b] = 0;
    __syncthreads();

    const float4* pts4 = reinterpret_cast<const float4*>(pts);
    const float4* ov4  = reinterpret_cast<const float4*>(occ_val);
    const int4*   bi4  = reinterpret_cast<const int4*>(bidx);

    // statically-indexed -> stays in VGPRs (rule #20)
    int pk[PTS_PER_THREAD];
    int bk[PTS_PER_THREAD];

    #pragma unroll
    for (int r = 0; r < PTS_PER_THREAD / 8; ++r) {
        // 8-point group id; block owns groups [c*512, c*512+512)
        const int i = c * ((PTS_PER_THREAD / 8) * 256) + r * 256 + tid;
        if (i * 8 + 7 < n_total) {
            float4 q0 = pts4[i * 6 + 0];
            float4 q1 = pts4[i * 6 + 1];
            float4 q2 = pts4[i * 6 + 2];
            float4 q3 = pts4[i * 6 + 3];
            float4 q4 = pts4[i * 6 + 4];
            float4 q5 = pts4[i * 6 + 5];
            float4 oa = ov4[i * 2 + 0];
            float4 ob = ov4[i * 2 + 1];
            int4   ba = bi4[i * 2 + 0];
            int4   bb = bi4[i * 2 + 1];

            float xs[8] = {q0.x, q0.w, q1.z, q2.y, q3.x, q3.w, q4.z, q5.y};
            float ys[8] = {q0.y, q1.x, q1.w, q2.z, q3.y, q4.x, q4.w, q5.z};
            float zs[8] = {q0.z, q1.y, q2.x, q2.w, q3.z, q4.y, q5.x, q5.w};
            int   vb[8] = {__float_as_int(oa.x), __float_as_int(oa.y),
                           __float_as_int(oa.z), __float_as_int(oa.w),
                           __float_as_int(ob.x), __float_as_int(ob.y),
                           __float_as_int(ob.z), __float_as_int(ob.w)};
            int   bs[8] = {ba.x, ba.y, ba.z, ba.w, bb.x, bb.y, bb.z, bb.w};

            #pragma unroll
            for (int k = 0; k < 8; ++k) {
                int gx = quant_clamp(xs[k]);
                int gy = quant_clamp(ys[k]);
                int gz = quant_clamp(zs[k]);
                int idx = bs[k] * (GRID_R * GRID_R * GRID_R)
                        + gx * (GRID_R * GRID_R) + gy * GRID_R + gz;
                pk[r * 8 + k] = (vb[k] & (int)0xFFFFC000) | (idx & 0x3FFF);
                bk[r * 8 + k] = idx >> 14;
            }
        } else {
            #pragma unroll
            for (int k = 0; k < 8; ++k) {
                bk[r * 8 + k] = -1;
                pk[r * 8 + k] = 0;
                int p = i * 8 + k;
                if (p < n_total) {
                    int gx = quant_clamp(pts[p * 3 + 0]);
                    int gy = quant_clamp(pts[p * 3 + 1]);
                    int gz = quant_clamp(pts[p * 3 + 2]);
                    int idx = bidx[p] * (GRID_R * GRID_R * GRID_R)
                            + gx * (GRID_R * GRID_R) + gy * GRID_R + gz;
                    pk[r * 8 + k] = (__float_as_int(occ_val[p]) & (int)0xFFFFC000)
                                  | (idx & 0x3FFF);
                    bk[r * 8 + k] = idx >> 14;
                }
            }
        }
    }

    // block-local histogram
    #pragma unroll
    for (int k = 0; k < PTS_PER_THREAD; ++k)
        if (bk[k] >= 0) atomicAdd(&cur[bk[k]], 1);
    __syncthreads();

    // thread t owns buckets {2t, 2t+1}; wave scan of pair-sums
    const int a = cur[2 * tid];
    const int cc = cur[2 * tid + 1];
    const int s = a + cc;
    int x = s;
    #pragma unroll
    for (int off = 1; off < 64; off <<= 1) {
        int v = __shfl_up(x, off, 64);
        if (lane >= off) x += v;
    }
    if (lane == 63) wsum[wv] = x;
    __syncthreads();

    const int w0 = wsum[0], w1 = wsum[1], w2 = wsum[2], w3 = wsum[3];
    const int wofs  = (wv > 0 ? w0 : 0) + (wv > 1 ? w1 : 0) + (wv > 2 ? w2 : 0);
    const int total = w0 + w1 + w2 + w3;
    const int excl  = x + wofs - s;     // exclusive prefix of bucket 2t

    // per-chunk offset table (transposed: row = bucket, col = chunk)
    offT[(size_t)(2 * tid)     * nchunk + c] = (unsigned short)excl;
    offT[(size_t)(2 * tid + 1) * nchunk + c] = (unsigned short)(excl + a);
    if (tid == 255)
        offT[(size_t)NBUCKET   * nchunk + c] = (unsigned short)total;

    cur[2 * tid]     = excl;
    cur[2 * tid + 1] = excl + a;
    __syncthreads();

    // multisplit into LDS (grouped by bucket)
    #pragma unroll
    for (int k = 0; k < PTS_PER_THREAD; ++k) {
        if (bk[k] >= 0) {
            int slot = atomicAdd(&cur[bk[k]], 1);
            rec[slot] = (unsigned)pk[k];
        }
    }
    __syncthreads();

    // dense, perfectly coalesced flush into this chunk's segment
    unsigned* dst = sorted + (size_t)c * PTS_PER_BLOCK;
    for (int j = tid; j < total; j += 256)
        dst[j] = rec[j];
}

// ------------------------------------------------------------------ K2
// One block per bucket, 512 threads: uint4-vectorized slice gather,
// LDS max, fused finalize.
__global__ __launch_bounds__(512)
void occ_bucket5_kernel(const unsigned*       __restrict__ sorted,
                        const unsigned short* __restrict__ offT,
                        const float*          __restrict__ grid,
                        float*                __restrict__ out,
                        int nchunk) {
    __shared__ int smax[VOX_PER_BUCKET];    // 64 KB
    const int tid = threadIdx.x;
    // XCD-chunked bucket assignment: adjacent logical buckets land on the
    // same XCD -> shared L2 lines for slice reads (512 = 8*64, bijective).
    const int b = (blockIdx.x & 7) * (NBUCKET / 8) + (blockIdx.x >> 3);

    int4* s4 = reinterpret_cast<int4*>(smax);
    for (int j = tid; j < VOX_PER_BUCKET / 4; j += 512)
        s4[j] = make_int4(-1, -1, -1, -1);
    __syncthreads();

    const unsigned short* rowLo = offT + (size_t)b       * nchunk;
    const unsigned short* rowHi = offT + (size_t)(b + 1) * nchunk;

    // thread per chunk; uint4 body with head/tail masking. Slices are
    // contiguous, so rounding lo down to a 16B boundary reads at most 3
    // extra records (masked; worst case 8B past the last chunk segment
    // lands in the allocated offT region).
    for (int c = tid; c < nchunk; c += 512) {
        const int lo = rowLo[c];
        const int hi = rowHi[c];
        const unsigned* rp = sorted + (size_t)c * PTS_PER_BLOCK;
        for (int j = (lo & ~3); j < hi; j += 4) {
            uint4 e = *reinterpret_cast<const uint4*>(rp + j);
            if (j     >= lo && j     < hi)
                atomicMax(&smax[e.x & (VOX_PER_BUCKET - 1)], (int)e.x);
            if (j + 1 >= lo && j + 1 < hi)
                atomicMax(&smax[e.y & (VOX_PER_BUCKET - 1)], (int)e.y);
            if (j + 2 >= lo && j + 2 < hi)
                atomicMax(&smax[e.z & (VOX_PER_BUCKET - 1)], (int)e.z);
            if (j + 3 >= lo && j + 3 < hi)
                atomicMax(&smax[e.w & (VOX_PER_BUCKET - 1)], (int)e.w);
        }
    }
    __syncthreads();

    // fused finalize: each voxel of this bucket written exactly once.
    // packed sign bit = occ sign = 0 -> packed >= 0 -> sentinel -1 unambiguous.
    const size_t vbase = (size_t)b * VOX_PER_BUCKET;
    const float4* g4  = reinterpret_cast<const float4*>(grid + vbase);
    float4*       o4  = reinterpret_cast<float4*>(out + vbase);
    const int4*   sm4 = reinterpret_cast<const int4*>(smax);
    for (int j = tid; j < VOX_PER_BUCKET / 4; j += 512) {
        int4   w = sm4[j];
        float4 g = g4[j];
        float4 r;
        r.x = (w.x == -1) ? g.x
            : fmaxf(EMA_DEC * g.x, __int_as_float(w.x & (int)0xFFFFC000));
        r.y = (w.y == -1) ? g.y
            : fmaxf(EMA_DEC * g.y, __int_as_float(w.y & (int)0xFFFFC000));
        r.z = (w.z == -1) ? g.z
            : fmaxf(EMA_DEC * g.z, __int_as_float(w.z & (int)0xFFFFC000));
        r.w = (w.w == -1) ? g.w
            : fmaxf(EMA_DEC * g.w, __int_as_float(w.w & (int)0xFFFFC000));
        o4[j] = r;
    }
}

// ------------------------------------------------- Fallback (proven R4 path)
__global__ void occ_scatter8_kernel(const float* __restrict__ pts,
                                    const float* __restrict__ occ_val,
                                    const int*   __restrict__ bidx,
                                    int*         __restrict__ out_bits,
                                    int n8, int n_total) {
    const int tid    = blockIdx.x * blockDim.x + threadIdx.x;
    const int stride = gridDim.x * blockDim.x;

    const float4* pts4 = reinterpret_cast<const float4*>(pts);
    const float4* ov4  = reinterpret_cast<const float4*>(occ_val);
    const int4*   bi4  = reinterpret_cast<const int4*>(bidx);

    for (int i = tid; i < n8; i += stride) {
        float4 q0 = pts4[i * 6 + 0];
        float4 q1 = pts4[i * 6 + 1];
        float4 q2 = pts4[i * 6 + 2];
        float4 q3 = pts4[i * 6 + 3];
        float4 q4 = pts4[i * 6 + 4];
        float4 q5 = pts4[i * 6 + 5];
        float4 oa = ov4[i * 2 + 0];
        float4 ob = ov4[i * 2 + 1];
        int4   ba = bi4[i * 2 + 0];
        int4   bb = bi4[i * 2 + 1];

        float xs[8] = {q0.x, q0.w, q1.z, q2.y, q3.x, q3.w, q4.z, q5.y};
        float ys[8] = {q0.y, q1.x, q1.w, q2.z, q3.y, q4.x, q4.w, q5.z};
        float zs[8] = {q0.z, q1.y, q2.x, q2.w, q3.z, q4.y, q5.x, q5.w};
        int   vb[8] = {__float_as_int(oa.x), __float_as_int(oa.y),
                       __float_as_int(oa.z), __float_as_int(oa.w),
                       __float_as_int(ob.x), __float_as_int(ob.y),
                       __float_as_int(ob.z), __float_as_int(ob.w)};
        int   bs[8] = {ba.x, ba.y, ba.z, ba.w, bb.x, bb.y, bb.z, bb.w};

        int idx[8];
        #pragma unroll
        for (int k = 0; k < 8; ++k) {
            int gx = quant_clamp(xs[k]);
            int gy = quant_clamp(ys[k]);
            int gz = quant_clamp(zs[k]);
            idx[k] = bs[k] * (GRID_R * GRID_R * GRID_R)
                   + gx * (GRID_R * GRID_R) + gy * GRID_R + gz;
        }
        #pragma unroll
        for (int k = 0; k < 8; ++k) atomicMax(&out_bits[idx[k]], vb[k]);
    }

    for (int i = n8 * 8 + tid; i < n_total; i += stride) {
        int gx = quant_clamp(pts[i * 3 + 0]);
        int gy = quant_clamp(pts[i * 3 + 1]);
        int gz = quant_clamp(pts[i * 3 + 2]);
        int idx = bidx[i] * (GRID_R * GRID_R * GRID_R)
                + gx * (GRID_R * GRID_R) + gy * GRID_R + gz;
        atomicMax(&out_bits[idx], __float_as_int(occ_val[i]));
    }
}

__global__ void occ_finalize_kernel(const float* __restrict__ grid,
                                    float*       __restrict__ out,
                                    int v4, int v_total) {
    const int tid    = blockIdx.x * blockDim.x + threadIdx.x;
    const int stride = gridDim.x * blockDim.x;

    const float4* g4 = reinterpret_cast<const float4*>(grid);
    int4*         w4 = reinterpret_cast<int4*>(out);
    float4*       o4 = reinterpret_cast<float4*>(out);

    for (int i = tid; i < v4; i += stride) {
        int4   w = w4[i];
        float4 g = g4[i];
        float4 r;
        r.x = (w.x == -1) ? g.x : fmaxf(EMA_DEC * g.x, __int_as_float(w.x));
        r.y = (w.y == -1) ? g.y : fmaxf(EMA_DEC * g.y, __int_as_float(w.y));
        r.z = (w.z == -1) ? g.z : fmaxf(EMA_DEC * g.z, __int_as_float(w.z));
        r.w = (w.w == -1) ? g.w : fmaxf(EMA_DEC * g.w, __int_as_float(w.w));
        o4[i] = r;
    }
    for (int i = v4 * 4 + tid; i < v_total; i += stride) {
        int w = reinterpret_cast<int*>(out)[i];
        float g = grid[i];
        out[i] = (w == -1) ? g : fmaxf(EMA_DEC * g, __int_as_float(w));
    }
}

// ---------------------------------------------------------------- launch
extern "C" void kernel_launch(void* const* d_in, const int* in_sizes, int n_in,
                              void* d_out, int out_size, void* d_ws, size_t ws_size,
                              hipStream_t stream) {
    const float* grid    = (const float*)d_in[0];   // (B,R,R,R) f32
    const float* pts     = (const float*)d_in[1];   // (N,3) f32
    const float* occ_val = (const float*)d_in[2];   // (N,) f32
    const int*   bidx    = (const int*)d_in[3];     // (N,) i32

    float* out = (float*)d_out;
    const int N = in_sizes[2];

    const int nchunk = (N + PTS_PER_BLOCK - 1) / PTS_PER_BLOCK;

    // ws layout: sorted[nchunk*4096] u32 | offT[513][nchunk] u16
    // (+16B slack so K2's uint4 overrun on the last chunk stays in-bounds)
    const size_t sorted_b = (size_t)nchunk * PTS_PER_BLOCK * sizeof(unsigned);
    const size_t off_b    = (size_t)(NBUCKET + 1) * nchunk * sizeof(unsigned short);
    const size_t need     = sorted_b + off_b + 16;
    const bool shape_ok   = (out_size == 4 * GRID_R * GRID_R * GRID_R);

    if (ws_size >= need && shape_ok && nchunk >= 1) {
        unsigned*       sorted = (unsigned*)d_ws;
        unsigned short* offT   = (unsigned short*)((char*)d_ws + sorted_b);

        occ_localsort_kernel<<<nchunk, 256, 0, stream>>>(
            pts, occ_val, bidx, sorted, offT, N, nchunk);
        occ_bucket5_kernel<<<NBUCKET, 512, 0, stream>>>(
            sorted, offT, grid, out, nchunk);
    } else {
        // fallback: sentinel memset + global atomic scatter + finalize
        hipMemsetAsync(d_out, 0xFF, (size_t)out_size * sizeof(float), stream);

        const int n8 = N / 8;
        int sblocks = (n8 + 255) / 256;
        if (sblocks < 1) sblocks = 1;
        occ_scatter8_kernel<<<sblocks, 256, 0, stream>>>(
            pts, occ_val, bidx, (int*)d_out, n8, N);

        const int v4 = out_size / 4;
        int fblocks = (v4 + 255) / 256;
        if (fblocks > 2048) fblocks = 2048;
        if (fblocks < 1) fblocks = 1;
        occ_finalize_kernel<<<fblocks, 256, 0, stream>>>(grid, out, v4, out_size);
    }
}